// Round 1
// baseline (856.489 us; speedup 1.0000x reference)
//
#include <hip/hip_runtime.h>

// Problem constants
constexpr int B  = 512, L = 50, N = 16, H = 128;
constexpr int C1 = 96, C2 = 48, C3 = 16;

// Padded LDS row strides (floats) — keep float4 alignment (stride % 4 == 0)
// and break power-of-2 bank patterns (stride % 32 != 0).
constexpr int PW  = 132;  // WaT rows (128 k)
constexpr int P1  = 100;  // W1T rows (96 k)
constexpr int P2  = 52;   // W2T rows (48 k)
constexpr int PN  = 132;  // neighbor rows (128)
constexpr int PS  = 100;  // score rows (96)
constexpr int PH1 = 52;   // h1 rows (48)
constexpr int PH2 = 20;   // h2 rows (16)

__device__ __forceinline__ float dot4acc(float4 a, float4 b, float acc) {
  acc = fmaf(a.x, b.x, acc);
  acc = fmaf(a.y, b.y, acc);
  acc = fmaf(a.z, b.z, acc);
  acc = fmaf(a.w, b.w, acc);
  return acc;
}

// Kernel A: per-b block. Gathers hist item rows, runs the attention MLP per
// (l, n), softmax over n, and accumulates mean_l of the attention-weighted
// neighbor aggregate into aggmean [B][H].
__global__ __launch_bounds__(256) void attn_agg_kernel(
    const int*   __restrict__ history,       // [B][L]
    const float* __restrict__ neighbor_emb,  // [B][L][N][H]
    const float* __restrict__ item_table,    // [100000][H]
    const float* __restrict__ Wa,  const float* __restrict__ ba,
    const float* __restrict__ W1,  const float* __restrict__ b1,
    const float* __restrict__ W2,  const float* __restrict__ b2,
    const float* __restrict__ W3,  const float* __restrict__ b3,
    float* __restrict__ aggmean)             // [B][H]
{
  __shared__ float sWaTtop[C1 * PW];  // Wa[k<128][j]   -> [j][k]
  __shared__ float sWaTbot[C1 * PW];  // Wa[k>=128][j]  -> [j][k-128]
  __shared__ float sW1T[C2 * P1];     // W1[k][j] -> [j][k]
  __shared__ float sW2T[C3 * P2];     // W2[k][j] -> [j][k]
  __shared__ float sNeigh[N * PN];
  __shared__ float sScore[N * PS];
  __shared__ float sH1[N * PH1];
  __shared__ float sH2[N * PH2];
  __shared__ float sHist[H];
  __shared__ float sHs[C1];
  __shared__ float sba[C1];
  __shared__ float sb1[C2];
  __shared__ float sb2[C3];
  __shared__ float sW3[C3];
  __shared__ float sLogit[N];
  __shared__ float sAttn[N];

  const int tid = threadIdx.x;
  const int b   = blockIdx.x;

  // ---- Stage + transpose all weights into LDS (once per block) ----
  for (int idx = tid; idx < 256 * C1; idx += 256) {
    int k = idx / C1, j = idx % C1;
    float v = Wa[idx];
    if (k < 128) sWaTtop[j * PW + k] = v;
    else         sWaTbot[j * PW + (k - 128)] = v;
  }
  for (int idx = tid; idx < C1 * C2; idx += 256) {
    int k = idx / C2, j = idx % C2;
    sW1T[j * P1 + k] = W1[idx];
  }
  for (int idx = tid; idx < C2 * C3; idx += 256) {
    int k = idx / C3, j = idx % C3;
    sW2T[j * P2 + k] = W2[idx];
  }
  if (tid < C1) sba[tid] = ba[tid];
  if (tid < C2) sb1[tid] = b1[tid];
  if (tid < C3) { sb2[tid] = b2[tid]; sW3[tid] = W3[tid]; }
  const float rb3 = b3[0];

  float aggacc = 0.f;  // valid for tid < H

  for (int l = 0; l < L; ++l) {
    __syncthreads();  // protects LDS from previous iteration / staging
    // ---- Load hist item row + neighbor tile ----
    {
      int item = history[b * L + l];
      const float4* hsrc = (const float4*)(item_table + (size_t)item * H);
      if (tid < H / 4) ((float4*)sHist)[tid] = hsrc[tid];
      const float4* nsrc =
          (const float4*)(neighbor_emb + (size_t)(b * L + l) * (N * H));
      for (int i = tid; i < N * H / 4; i += 256) {
        int e = i * 4;
        int n = e >> 7, k = e & 127;
        *(float4*)&sNeigh[n * PN + k] = nsrc[i];
      }
    }
    __syncthreads();

    // ---- Layer1, hist part (shared across all 16 neighbors) ----
    if (tid < C1) {
      const float* wr = &sWaTtop[tid * PW];
      float acc = sba[tid];
      #pragma unroll 8
      for (int k = 0; k < H; k += 4)
        acc = dot4acc(*(const float4*)&sHist[k], *(const float4*)&wr[k], acc);
      sHs[tid] = acc;
    }
    __syncthreads();

    // ---- Layer1, neighbor part: 2 neighbors x 3 cols per thread ----
    {
      const int n0i = (tid >> 5) * 2;       // 0,2,..,14
      const int j0  = (tid & 31) * 3;       // 0,3,..,93
      float a00 = 0, a01 = 0, a02 = 0, a10 = 0, a11 = 0, a12 = 0;
      const float* nr0 = &sNeigh[n0i * PN];
      const float* nr1 = &sNeigh[(n0i + 1) * PN];
      const float* w0  = &sWaTbot[j0 * PW];
      const float* w1  = &sWaTbot[(j0 + 1) * PW];
      const float* w2  = &sWaTbot[(j0 + 2) * PW];
      #pragma unroll 4
      for (int k = 0; k < H; k += 4) {
        float4 x0 = *(const float4*)&nr0[k];
        float4 x1 = *(const float4*)&nr1[k];
        float4 v0 = *(const float4*)&w0[k];
        float4 v1 = *(const float4*)&w1[k];
        float4 v2 = *(const float4*)&w2[k];
        a00 = dot4acc(x0, v0, a00); a01 = dot4acc(x0, v1, a01); a02 = dot4acc(x0, v2, a02);
        a10 = dot4acc(x1, v0, a10); a11 = dot4acc(x1, v1, a11); a12 = dot4acc(x1, v2, a12);
      }
      sScore[n0i * PS + j0 + 0] = fmaxf(a00 + sHs[j0 + 0], 0.f);
      sScore[n0i * PS + j0 + 1] = fmaxf(a01 + sHs[j0 + 1], 0.f);
      sScore[n0i * PS + j0 + 2] = fmaxf(a02 + sHs[j0 + 2], 0.f);
      sScore[(n0i + 1) * PS + j0 + 0] = fmaxf(a10 + sHs[j0 + 0], 0.f);
      sScore[(n0i + 1) * PS + j0 + 1] = fmaxf(a11 + sHs[j0 + 1], 0.f);
      sScore[(n0i + 1) * PS + j0 + 2] = fmaxf(a12 + sHs[j0 + 2], 0.f);
    }
    __syncthreads();

    // ---- Layer2: 96 -> 48, 1 neighbor x 3 cols per thread ----
    {
      const int n  = tid >> 4;
      const int j0 = (tid & 15) * 3;
      float a0 = sb1[j0], a1 = sb1[j0 + 1], a2 = sb1[j0 + 2];
      const float* sr = &sScore[n * PS];
      const float* w0 = &sW1T[j0 * P1];
      const float* w1 = &sW1T[(j0 + 1) * P1];
      const float* w2 = &sW1T[(j0 + 2) * P1];
      #pragma unroll 4
      for (int k = 0; k < C1; k += 4) {
        float4 sv = *(const float4*)&sr[k];
        a0 = dot4acc(sv, *(const float4*)&w0[k], a0);
        a1 = dot4acc(sv, *(const float4*)&w1[k], a1);
        a2 = dot4acc(sv, *(const float4*)&w2[k], a2);
      }
      sH1[n * PH1 + j0 + 0] = fmaxf(a0, 0.f);
      sH1[n * PH1 + j0 + 1] = fmaxf(a1, 0.f);
      sH1[n * PH1 + j0 + 2] = fmaxf(a2, 0.f);
    }
    __syncthreads();

    // ---- Layer3: 48 -> 16, one output per thread ----
    {
      const int n = tid >> 4, j = tid & 15;
      float acc = sb2[j];
      const float* hr = &sH1[n * PH1];
      const float* wr = &sW2T[j * P2];
      #pragma unroll
      for (int k = 0; k < C2; k += 4)
        acc = dot4acc(*(const float4*)&hr[k], *(const float4*)&wr[k], acc);
      sH2[n * PH2 + j] = fmaxf(acc, 0.f);
    }
    __syncthreads();

    // ---- Layer4 logits ----
    if (tid < N) {
      float acc = rb3;
      const float* hr = &sH2[tid * PH2];
      #pragma unroll
      for (int k = 0; k < C3; ++k) acc = fmaf(hr[k], sW3[k], acc);
      sLogit[tid] = acc;
    }
    __syncthreads();

    // ---- Softmax over 16 neighbors (redundant across 16 lanes; tiny) ----
    if (tid < N) {
      float m = sLogit[0];
      #pragma unroll
      for (int k = 1; k < N; ++k) m = fmaxf(m, sLogit[k]);
      float s = 0.f;
      #pragma unroll
      for (int k = 0; k < N; ++k) s += __expf(sLogit[k] - m);
      sAttn[tid] = __expf(sLogit[tid] - m) / s;
    }
    __syncthreads();

    // ---- Weighted aggregate, accumulated across l ----
    if (tid < H) {
      float acc = 0.f;
      #pragma unroll
      for (int n = 0; n < N; ++n)
        acc = fmaf(sAttn[n], sNeigh[n * PN + tid], acc);
      aggacc += acc;
    }
  }

  if (tid < H) aggmean[b * H + tid] = aggacc * (1.0f / L);
}

// Kernel B: fused head. pooled = aggmean @ Wmh + bmh (mean/matmul commuted),
// comb = [user_emb, pooled], hidden = relu(comb @ Wfc1 + bfc1),
// out = sigmoid(hidden @ Wout + bout).
__global__ __launch_bounds__(128) void head_kernel(
    const int*   __restrict__ user_ids,
    const float* __restrict__ user_table,
    const float* __restrict__ aggmean,
    const float* __restrict__ Wmh,  const float* __restrict__ bmh,
    const float* __restrict__ Wfc1, const float* __restrict__ bfc1,
    const float* __restrict__ Wout, const float* __restrict__ bout,
    float* __restrict__ out)
{
  __shared__ float sComb[2 * H];
  __shared__ float sAgg[H];
  __shared__ float sRed[2];
  const int t = threadIdx.x, b = blockIdx.x;

  int uid = user_ids[b];
  sComb[t] = user_table[(size_t)uid * H + t];
  sAgg[t]  = aggmean[b * H + t];
  __syncthreads();

  float p = bmh[t];
  #pragma unroll 4
  for (int k = 0; k < H; ++k) p = fmaf(sAgg[k], Wmh[k * H + t], p);
  sComb[H + t] = p;
  __syncthreads();

  float hd = bfc1[t];
  #pragma unroll 4
  for (int k = 0; k < 2 * H; ++k) hd = fmaf(sComb[k], Wfc1[k * H + t], hd);
  hd = fmaxf(hd, 0.f);

  float v = hd * Wout[t];
  #pragma unroll
  for (int off = 32; off > 0; off >>= 1) v += __shfl_down(v, off);
  if ((t & 63) == 0) sRed[t >> 6] = v;
  __syncthreads();
  if (t == 0) {
    float s = sRed[0] + sRed[1] + bout[0];
    out[b] = 1.f / (1.f + __expf(-s));
  }
}

extern "C" void kernel_launch(void* const* d_in, const int* in_sizes, int n_in,
                              void* d_out, int out_size, void* d_ws, size_t ws_size,
                              hipStream_t stream) {
  const int*   user_ids     = (const int*)  d_in[0];
  // d_in[1] = item_ids — unused (item_emb is computed but unused in reference)
  const int*   history      = (const int*)  d_in[2];
  const float* neighbor_emb = (const float*)d_in[3];
  const float* user_table   = (const float*)d_in[4];
  const float* item_table   = (const float*)d_in[5];
  const float* Wa   = (const float*)d_in[6];
  const float* ba   = (const float*)d_in[7];
  const float* W1   = (const float*)d_in[8];
  const float* b1   = (const float*)d_in[9];
  const float* W2   = (const float*)d_in[10];
  const float* b2   = (const float*)d_in[11];
  const float* W3   = (const float*)d_in[12];
  const float* b3   = (const float*)d_in[13];
  const float* Wmh  = (const float*)d_in[14];
  const float* bmh  = (const float*)d_in[15];
  const float* Wfc1 = (const float*)d_in[16];
  const float* bfc1 = (const float*)d_in[17];
  const float* Wout = (const float*)d_in[18];
  const float* bout = (const float*)d_in[19];

  float* aggmean = (float*)d_ws;     // [B][H] = 256 KB
  float* out     = (float*)d_out;    // [B]

  hipLaunchKernelGGL(attn_agg_kernel, dim3(B), dim3(256), 0, stream,
                     history, neighbor_emb, item_table,
                     Wa, ba, W1, b1, W2, b2, W3, b3, aggmean);
  hipLaunchKernelGGL(head_kernel, dim3(B), dim3(128), 0, stream,
                     user_ids, user_table, aggmean,
                     Wmh, bmh, Wfc1, bfc1, Wout, bout, out);
}

// Round 2
// 180.252 us; speedup vs baseline: 4.7516x; 4.7516x over previous
//
#include <hip/hip_runtime.h>

// Problem constants
constexpr int B  = 512, L = 50, N = 16, H = 128;
constexpr int C1 = 96, C2 = 48, C3 = 16;

typedef __bf16 bf16x8 __attribute__((ext_vector_type(8)));
typedef float  f32x4  __attribute__((ext_vector_type(4)));

// Fragment-staged weight tile counts (16x16x32 MFMA: N-tiles x K-steps)
constexpr int WA_FRAGS = 6 * 8;  // Wa: [256][96] -> K=256 (8 steps), N=96 (6 tiles)
constexpr int W1_FRAGS = 3 * 3;  // W1: [96][48]
constexpr int W2_FRAGS = 2;      // W2: [48][16], K padded 48->64 (2 steps), zeros above 48

// Per-wave LDS scratch strides (bf16 elems). Chosen so ds_read_b128 A-frag
// reads are <=2-way bank conflicts (free) and rows stay 16B-aligned.
constexpr int SC_STRIDE = 104;   // scores rows (96 data + 8 pad)
constexpr int H1_STRIDE = 72;    // h1 rows (48 data + 16 zero + 8 pad)

__device__ __forceinline__ bf16x8 cvt8(float4 a, float4 b) {
  bf16x8 r;
  r[0] = (__bf16)a.x; r[1] = (__bf16)a.y; r[2] = (__bf16)a.z; r[3] = (__bf16)a.w;
  r[4] = (__bf16)b.x; r[5] = (__bf16)b.y; r[6] = (__bf16)b.z; r[7] = (__bf16)b.w;
  return r;
}

// MFMA lane mapping (16x16x32 bf16, verified m89/m91):
//   A-frag: row = lane&15, k = 32*step + 8*(lane>>4) + j   (j = 0..7)
//   B-frag: col = lane&15, k = 32*step + 8*(lane>>4) + j
//   C/D   : col = lane&15, row = 4*(lane>>4) + reg
__global__ __launch_bounds__(512, 2) void attn_agg_kernel(
    const int*   __restrict__ history,       // [B][L]
    const float* __restrict__ neighbor_emb,  // [B][L][N][H]
    const float* __restrict__ item_table,    // [100000][H]
    const float* __restrict__ Wa,  const float* __restrict__ ba,
    const float* __restrict__ W1,  const float* __restrict__ b1,
    const float* __restrict__ W2,  const float* __restrict__ b2,
    const float* __restrict__ W3,
    float* __restrict__ aggmean)             // [B][H]
{
  __shared__ __bf16 sWa[WA_FRAGS * 64 * 8];  // 48 KB: pre-arranged B-frags
  __shared__ __bf16 sW1[W1_FRAGS * 64 * 8];  //  9 KB
  __shared__ __bf16 sW2[W2_FRAGS * 64 * 8];  //  2 KB
  __shared__ __bf16 sScores[8][16 * SC_STRIDE];  // 26 KB (per-wave)
  __shared__ __bf16 sH1[8][16 * H1_STRIDE];      // 18 KB (per-wave)
  __shared__ float  sAggRed[8][128];             //  4 KB

  const int tid  = threadIdx.x;
  const int wave = tid >> 6;
  const int lane = tid & 63;
  const int g    = lane >> 4;   // k-group within fragment
  const int c    = lane & 15;   // A-row / B-col / D-col

  // ---- Stage weights as pre-arranged lane fragments (once per block) ----
  // Each thread builds one full 8-elem lane fragment -> single 16B LDS store
  // (contiguous stride-16B across lanes = conflict-free).
  for (int e = tid; e < WA_FRAGS * 64; e += 512) {
    int lv = e & 63, frag = e >> 6;
    int s = frag & 7, t = frag >> 3;
    int k0 = s * 32 + ((lv >> 4) << 3);
    int cc = t * 16 + (lv & 15);
    bf16x8 v;
    #pragma unroll
    for (int j = 0; j < 8; ++j) v[j] = (__bf16)Wa[(k0 + j) * C1 + cc];
    *(bf16x8*)&sWa[e * 8] = v;
  }
  for (int e = tid; e < W1_FRAGS * 64; e += 512) {
    int lv = e & 63, frag = e >> 6;
    int s = frag % 3, t = frag / 3;
    int k0 = s * 32 + ((lv >> 4) << 3);
    int cc = t * 16 + (lv & 15);
    bf16x8 v;
    #pragma unroll
    for (int j = 0; j < 8; ++j) v[j] = (__bf16)W1[(k0 + j) * C2 + cc];
    *(bf16x8*)&sW1[e * 8] = v;
  }
  for (int e = tid; e < W2_FRAGS * 64; e += 512) {
    int lv = e & 63, s = e >> 6;
    int k0 = s * 32 + ((lv >> 4) << 3);
    int cc = lv & 15;
    bf16x8 v;
    #pragma unroll
    for (int j = 0; j < 8; ++j)
      v[j] = (k0 + j < C2) ? (__bf16)W2[(k0 + j) * C3 + cc] : (__bf16)0.f;
    *(bf16x8*)&sW2[e * 8] = v;
  }
  // Zero sH1 (cols 48..63 must be exact zeros for the padded K=64 read;
  // epilogue only ever rewrites cols 0..47, so zeros persist).
  for (int i = tid; i < 8 * 16 * H1_STRIDE / 2; i += 512)
    ((unsigned int*)sH1)[i] = 0u;

  // Per-lane bias/W3 registers (tiny broadcast loads, L1-hot)
  float ba_r[6], b1_r[3];
  #pragma unroll
  for (int t = 0; t < 6; ++t) ba_r[t] = ba[t * 16 + c];
  #pragma unroll
  for (int t = 0; t < 3; ++t) b1_r[t] = b1[t * 16 + c];
  const float b2_r = b2[c];
  const float w3_r = W3[c];

  __syncthreads();

  // W2 fragments live in registers (2 frags = 8 VGPRs)
  bf16x8 w2f[2];
  #pragma unroll
  for (int s = 0; s < 2; ++s) w2f[s] = *(const bf16x8*)&sW2[(s * 64 + lane) * 8];

  // ---- Main loop: one wave per (b,l) pair, no block barriers ----
  const int bb = blockIdx.x * 2 + (wave >> 2);
  const int wl = wave & 3;
  __bf16* myScores = sScores[wave];
  __bf16* myH1     = sH1[wave];
  float agg0 = 0.f, agg1 = 0.f;

  for (int li = wl; li < L; li += 4) {
    const float* hrow = item_table + (size_t)history[bb * L + li] * H;
    const float* nb   = neighbor_emb + (size_t)(bb * L + li) * (N * H);

    // A-frags: K=0..127 = hist broadcast (same for all 16 rows),
    //          K=128..255 = neighbor rows.
    bf16x8 a[8];
    #pragma unroll
    for (int s = 0; s < 4; ++s) {
      const float* p = hrow + s * 32 + g * 8;
      a[s] = cvt8(*(const float4*)p, *(const float4*)(p + 4));
    }
    #pragma unroll
    for (int s = 0; s < 4; ++s) {
      const float* p = nb + c * H + s * 32 + g * 8;
      a[4 + s] = cvt8(*(const float4*)p, *(const float4*)(p + 4));
    }

    // ---- Layer 1: [16,256] @ [256,96] ----
    f32x4 acc[6];
    #pragma unroll
    for (int t = 0; t < 6; ++t) acc[t] = (f32x4){0.f, 0.f, 0.f, 0.f};
    #pragma unroll
    for (int s = 0; s < 8; ++s)
      #pragma unroll
      for (int t = 0; t < 6; ++t)
        acc[t] = __builtin_amdgcn_mfma_f32_16x16x32_bf16(
            a[s], *(const bf16x8*)&sWa[((t * 8 + s) * 64 + lane) * 8], acc[t],
            0, 0, 0);
    #pragma unroll
    for (int t = 0; t < 6; ++t)
      #pragma unroll
      for (int r = 0; r < 4; ++r)
        myScores[(g * 4 + r) * SC_STRIDE + t * 16 + c] =
            (__bf16)fmaxf(acc[t][r] + ba_r[t], 0.f);

    // ---- Layer 2: [16,96] @ [96,48] ----
    bf16x8 a2[3];
    #pragma unroll
    for (int s = 0; s < 3; ++s)
      a2[s] = *(const bf16x8*)&myScores[c * SC_STRIDE + s * 32 + g * 8];
    f32x4 acc2[3];
    #pragma unroll
    for (int t = 0; t < 3; ++t) acc2[t] = (f32x4){0.f, 0.f, 0.f, 0.f};
    #pragma unroll
    for (int s = 0; s < 3; ++s)
      #pragma unroll
      for (int t = 0; t < 3; ++t)
        acc2[t] = __builtin_amdgcn_mfma_f32_16x16x32_bf16(
            a2[s], *(const bf16x8*)&sW1[((t * 3 + s) * 64 + lane) * 8], acc2[t],
            0, 0, 0);
    #pragma unroll
    for (int t = 0; t < 3; ++t)
      #pragma unroll
      for (int r = 0; r < 4; ++r)
        myH1[(g * 4 + r) * H1_STRIDE + t * 16 + c] =
            (__bf16)fmaxf(acc2[t][r] + b1_r[t], 0.f);

    // ---- Layer 3: [16,48(->64)] @ [64,16] ----
    bf16x8 a3[2];
    #pragma unroll
    for (int s = 0; s < 2; ++s)
      a3[s] = *(const bf16x8*)&myH1[c * H1_STRIDE + s * 32 + g * 8];
    f32x4 acc3 = (f32x4){0.f, 0.f, 0.f, 0.f};
    #pragma unroll
    for (int s = 0; s < 2; ++s)
      acc3 = __builtin_amdgcn_mfma_f32_16x16x32_bf16(a3[s], w2f[s], acc3, 0, 0, 0);

    // ---- Layer 4 logits + softmax (per wave; b3 cancels in softmax) ----
    // lane holds h2 rows 4g+r at col c; logit[row] = sum_c h2[row][c]*W3[c]
    float lp[4];
    #pragma unroll
    for (int r = 0; r < 4; ++r)
      lp[r] = fmaxf(acc3[r] + b2_r, 0.f) * w3_r;
    #pragma unroll
    for (int off = 1; off < 16; off <<= 1)
      #pragma unroll
      for (int r = 0; r < 4; ++r) lp[r] += __shfl_xor(lp[r], off);
    float attn[16];
    #pragma unroll
    for (int n = 0; n < 16; ++n) attn[n] = __shfl(lp[n & 3], (n >> 2) << 4);
    float m = attn[0];
    #pragma unroll
    for (int n = 1; n < 16; ++n) m = fmaxf(m, attn[n]);
    float ssum = 0.f;
    #pragma unroll
    for (int n = 0; n < 16; ++n) { attn[n] = __expf(attn[n] - m); ssum += attn[n]; }
    const float rs = 1.f / ssum;

    // ---- Weighted aggregate: agg[h] += sum_n attn[n]*neigh[n][h] ----
    // lane handles h = {2*lane, 2*lane+1}; coalesced float2, L1/L2-hot.
    #pragma unroll
    for (int n = 0; n < 16; ++n) {
      float2 v = *(const float2*)(nb + n * H + 2 * lane);
      float w = attn[n] * rs;
      agg0 = fmaf(w, v.x, agg0);
      agg1 = fmaf(w, v.y, agg1);
    }
  }

  sAggRed[wave][2 * lane]     = agg0;
  sAggRed[wave][2 * lane + 1] = agg1;
  __syncthreads();

  if (tid < 256) {
    int bs = tid >> 7, h = tid & 127;
    float s = 0.f;
    #pragma unroll
    for (int w = 0; w < 4; ++w) s += sAggRed[bs * 4 + w][h];
    aggmean[(size_t)(blockIdx.x * 2 + bs) * H + h] = s * (1.0f / L);
  }
}

// Kernel B: fused head. pooled = aggmean @ Wmh + bmh (mean/matmul commuted),
// comb = [user_emb, pooled], hidden = relu(comb @ Wfc1 + bfc1),
// out = sigmoid(hidden @ Wout + bout).
__global__ __launch_bounds__(128) void head_kernel(
    const int*   __restrict__ user_ids,
    const float* __restrict__ user_table,
    const float* __restrict__ aggmean,
    const float* __restrict__ Wmh,  const float* __restrict__ bmh,
    const float* __restrict__ Wfc1, const float* __restrict__ bfc1,
    const float* __restrict__ Wout, const float* __restrict__ bout,
    float* __restrict__ out)
{
  __shared__ float sComb[2 * H];
  __shared__ float sAgg[H];
  __shared__ float sRed[2];
  const int t = threadIdx.x, b = blockIdx.x;

  int uid = user_ids[b];
  sComb[t] = user_table[(size_t)uid * H + t];
  sAgg[t]  = aggmean[b * H + t];
  __syncthreads();

  float p = bmh[t];
  #pragma unroll 4
  for (int k = 0; k < H; ++k) p = fmaf(sAgg[k], Wmh[k * H + t], p);
  sComb[H + t] = p;
  __syncthreads();

  float hd = bfc1[t];
  #pragma unroll 4
  for (int k = 0; k < 2 * H; ++k) hd = fmaf(sComb[k], Wfc1[k * H + t], hd);
  hd = fmaxf(hd, 0.f);

  float v = hd * Wout[t];
  #pragma unroll
  for (int off = 32; off > 0; off >>= 1) v += __shfl_down(v, off);
  if ((t & 63) == 0) sRed[t >> 6] = v;
  __syncthreads();
  if (t == 0) {
    float s = sRed[0] + sRed[1] + bout[0];
    out[b] = 1.f / (1.f + __expf(-s));
  }
}

extern "C" void kernel_launch(void* const* d_in, const int* in_sizes, int n_in,
                              void* d_out, int out_size, void* d_ws, size_t ws_size,
                              hipStream_t stream) {
  const int*   user_ids     = (const int*)  d_in[0];
  // d_in[1] = item_ids — unused (item_emb is computed but unused in reference)
  const int*   history      = (const int*)  d_in[2];
  const float* neighbor_emb = (const float*)d_in[3];
  const float* user_table   = (const float*)d_in[4];
  const float* item_table   = (const float*)d_in[5];
  const float* Wa   = (const float*)d_in[6];
  const float* ba   = (const float*)d_in[7];
  const float* W1   = (const float*)d_in[8];
  const float* b1   = (const float*)d_in[9];
  const float* W2   = (const float*)d_in[10];
  const float* b2   = (const float*)d_in[11];
  const float* W3   = (const float*)d_in[12];
  // d_in[13] = b3 — constant shift over the softmax axis, cancels exactly
  const float* Wmh  = (const float*)d_in[14];
  const float* bmh  = (const float*)d_in[15];
  const float* Wfc1 = (const float*)d_in[16];
  const float* bfc1 = (const float*)d_in[17];
  const float* Wout = (const float*)d_in[18];
  const float* bout = (const float*)d_in[19];

  float* aggmean = (float*)d_ws;     // [B][H] = 256 KB
  float* out     = (float*)d_out;    // [B]

  hipLaunchKernelGGL(attn_agg_kernel, dim3(B / 2), dim3(512), 0, stream,
                     history, neighbor_emb, item_table,
                     Wa, ba, W1, b1, W2, b2, W3, aggmean);
  hipLaunchKernelGGL(head_kernel, dim3(B), dim3(128), 0, stream,
                     user_ids, user_table, aggmean,
                     Wmh, bmh, Wfc1, bfc1, Wout, bout, out);
}

// Round 3
// 87.037 us; speedup vs baseline: 9.8406x; 2.0710x over previous
//
#include <hip/hip_runtime.h>

// Problem constants
constexpr int B  = 512, L = 50, N = 16, H = 128;
constexpr int C1 = 96, C2 = 48, C3 = 16;

typedef __bf16 bf16x8 __attribute__((ext_vector_type(8)));
typedef float  f32x4  __attribute__((ext_vector_type(4)));

// Per-wave LDS scratch layout (bf16 element offsets within sPW[wave])
constexpr int OFF_NE = 0;      // 16x128 neighbor tile, 16B-slot XOR swizzle
constexpr int OFF_HS = 2048;   // 16x96 hist-scores (+ba), row = l-iteration
constexpr int OFF_SC = 3584;   // scores, 16 rows x SC_STRIDE
constexpr int OFF_H1 = 5248;   // h1, 16 rows x H1_STRIDE (cols 48..63 = 0)
constexpr int PW_SIZE   = 6400;  // 12.8 KB per wave
constexpr int SC_STRIDE = 104;   // 208 B rows: 16B-aligned, non-pow2 bank spread
constexpr int H1_STRIDE = 72;    // 144 B rows

__device__ __forceinline__ bf16x8 cvt8(float4 a, float4 b) {
  bf16x8 r;
  r[0] = (__bf16)a.x; r[1] = (__bf16)a.y; r[2] = (__bf16)a.z; r[3] = (__bf16)a.w;
  r[4] = (__bf16)b.x; r[5] = (__bf16)b.y; r[6] = (__bf16)b.z; r[7] = (__bf16)b.w;
  return r;
}
__device__ __forceinline__ float bf16lo(unsigned u) { return __uint_as_float(u << 16); }
__device__ __forceinline__ float bf16hi(unsigned u) { return __uint_as_float(u & 0xffff0000u); }

// MFMA 16x16x32 bf16 lane mapping (verified m89/m91):
//   A: row = lane&15, k = 32*step + 8*(lane>>4) + j
//   B: col = lane&15, k = 32*step + 8*(lane>>4) + j
//   D: col = lane&15, row = 4*(lane>>4) + reg
__global__ __launch_bounds__(512, 2) void attn_agg_kernel(
    const int*   __restrict__ history,       // [B][L]
    const float* __restrict__ neighbor_emb,  // [B][L][N][H]
    const float* __restrict__ item_table,    // [100000][H]
    const float* __restrict__ Wa,  const float* __restrict__ ba,
    const float* __restrict__ W1,  const float* __restrict__ b1,
    const float* __restrict__ W2,  const float* __restrict__ b2,
    const float* __restrict__ W3,
    float* __restrict__ aggmean)             // [B][H]
{
  __shared__ __align__(16) __bf16 sWa[48 * 64 * 8];   // 48 KB, frag f = t*8+s
  __shared__ __align__(16) __bf16 sW1[9 * 64 * 8];    //  9 KB, frag f = t*3+s
  __shared__ __align__(16) __bf16 sPW[8][PW_SIZE];    // 100 KB per-wave scratch

  const int tid  = threadIdx.x;
  const int wave = tid >> 6;
  const int lane = tid & 63;
  const int g    = lane >> 4;   // k-group
  const int c    = lane & 15;   // A-row / B-col / D-col

  // ---- Stage Wa/W1 as pre-arranged lane fragments (contiguous 16B/lane) ----
  for (int e = tid; e < 48 * 64; e += 512) {
    int lv = e & 63, frag = e >> 6;
    int s = frag & 7, t = frag >> 3;
    int k0 = s * 32 + ((lv >> 4) << 3);
    int cc = t * 16 + (lv & 15);
    bf16x8 v;
    #pragma unroll
    for (int j = 0; j < 8; ++j) v[j] = (__bf16)Wa[(k0 + j) * C1 + cc];
    *(bf16x8*)&sWa[e * 8] = v;
  }
  for (int e = tid; e < 9 * 64; e += 512) {
    int lv = e & 63, frag = e >> 6;
    int s = frag % 3, t = frag / 3;
    int k0 = s * 32 + ((lv >> 4) << 3);
    int cc = t * 16 + (lv & 15);
    bf16x8 v;
    #pragma unroll
    for (int j = 0; j < 8; ++j) v[j] = (__bf16)W1[(k0 + j) * C2 + cc];
    *(bf16x8*)&sW1[e * 8] = v;
  }
  // Zero all H1 regions (cols 48..63 must stay 0 for the K=64-padded layer 3)
  for (int i = tid; i < 8 * (16 * H1_STRIDE / 2); i += 512) {
    int w = i / (16 * H1_STRIDE / 2), r = i % (16 * H1_STRIDE / 2);
    ((unsigned*)&sPW[w][OFF_H1])[r] = 0u;
  }

  // Per-lane constants
  float ba_r[6], b1_r[3];
  #pragma unroll
  for (int t = 0; t < 6; ++t) ba_r[t] = ba[t * 16 + c];
  #pragma unroll
  for (int t = 0; t < 3; ++t) b1_r[t] = b1[t * 16 + c];
  const float b2_r = b2[c];
  const float w3_r = W3[c];
  // W2 fragments straight from global into registers (K padded 48->64)
  bf16x8 w2f[2];
  #pragma unroll
  for (int s = 0; s < 2; ++s)
    #pragma unroll
    for (int j = 0; j < 8; ++j) {
      int k = s * 32 + g * 8 + j;
      w2f[s][j] = (k < C2) ? (__bf16)W2[k * C3 + c] : (__bf16)0.f;
    }

  __syncthreads();

  const int bb = blockIdx.x * 2 + (wave >> 2);
  const int wl = wave & 3;
  __bf16* PW = sPW[wave];
  const int nIter = (L - wl + 3) / 4;   // 13,13,12,12

  // ---- Prologue: batched hist GEMM over this wave's l's (rows = it) ----
  {
    int li  = wl + 4 * c;
    int idx = (li < L) ? history[bb * L + li] : history[bb * L];
    const float* hr = item_table + (size_t)idx * H;
    f32x4 acch[6];
    #pragma unroll
    for (int t = 0; t < 6; ++t) acch[t] = (f32x4){0.f, 0.f, 0.f, 0.f};
    #pragma unroll
    for (int s = 0; s < 4; ++s) {
      const float* p = hr + s * 32 + g * 8;
      bf16x8 a = cvt8(*(const float4*)p, *(const float4*)(p + 4));
      #pragma unroll
      for (int t = 0; t < 6; ++t)
        acch[t] = __builtin_amdgcn_mfma_f32_16x16x32_bf16(
            a, *(const bf16x8*)&sWa[((t * 8 + s) * 64 + lane) * 8], acch[t], 0, 0, 0);
    }
    #pragma unroll
    for (int t = 0; t < 6; ++t)
      #pragma unroll
      for (int r = 0; r < 4; ++r)
        PW[OFF_HS + (4 * g + r) * 96 + t * 16 + c] = (__bf16)(acch[t][r] + ba_r[t]);
  }

  // ---- Main loop: pipelined neighbor-tile MLP + softmax + aggregate ----
  float agg0 = 0.f, agg1 = 0.f;
  float4 nf[8];
  {
    const float* p = neighbor_emb + (size_t)(bb * L + wl) * (N * H) + c * H + g * 8;
    #pragma unroll
    for (int s = 0; s < 4; ++s) {
      nf[2 * s]     = *(const float4*)(p + s * 32);
      nf[2 * s + 1] = *(const float4*)(p + s * 32 + 4);
    }
  }

  for (int it = 0; it < nIter; ++it) {
    // Stage tile `it` into per-wave LDS (bf16, XOR-swizzled 16B slots)
    #pragma unroll
    for (int s = 0; s < 4; ++s) {
      int slot = (4 * s + g) ^ c;
      *(bf16x8*)&PW[OFF_NE + c * 128 + slot * 8] = cvt8(nf[2 * s], nf[2 * s + 1]);
    }
    // Prefetch tile it+1 (latency hides under compute below)
    if (it + 1 < nIter) {
      const float* p = neighbor_emb +
          (size_t)(bb * L + wl + 4 * (it + 1)) * (N * H) + c * H + g * 8;
      #pragma unroll
      for (int s = 0; s < 4; ++s) {
        nf[2 * s]     = *(const float4*)(p + s * 32);
        nf[2 * s + 1] = *(const float4*)(p + s * 32 + 4);
      }
    }

    // Layer 1 (neighbor half, K=128) + hist-scores add + relu
    f32x4 acc[6];
    #pragma unroll
    for (int t = 0; t < 6; ++t) acc[t] = (f32x4){0.f, 0.f, 0.f, 0.f};
    #pragma unroll
    for (int s = 0; s < 4; ++s) {
      bf16x8 a = *(const bf16x8*)&PW[OFF_NE + c * 128 + (((4 * s + g) ^ c)) * 8];
      #pragma unroll
      for (int t = 0; t < 6; ++t)
        acc[t] = __builtin_amdgcn_mfma_f32_16x16x32_bf16(
            a, *(const bf16x8*)&sWa[((t * 8 + 4 + s) * 64 + lane) * 8], acc[t], 0, 0, 0);
    }
    float hs[6];
    #pragma unroll
    for (int t = 0; t < 6; ++t) hs[t] = (float)PW[OFF_HS + it * 96 + t * 16 + c];
    #pragma unroll
    for (int t = 0; t < 6; ++t)
      #pragma unroll
      for (int r = 0; r < 4; ++r)
        PW[OFF_SC + (4 * g + r) * SC_STRIDE + t * 16 + c] =
            (__bf16)fmaxf(acc[t][r] + hs[t], 0.f);

    // Layer 2: [16,96] @ [96,48]
    f32x4 acc2[3];
    #pragma unroll
    for (int t = 0; t < 3; ++t) acc2[t] = (f32x4){0.f, 0.f, 0.f, 0.f};
    #pragma unroll
    for (int s = 0; s < 3; ++s) {
      bf16x8 a2 = *(const bf16x8*)&PW[OFF_SC + c * SC_STRIDE + s * 32 + g * 8];
      #pragma unroll
      for (int t = 0; t < 3; ++t)
        acc2[t] = __builtin_amdgcn_mfma_f32_16x16x32_bf16(
            a2, *(const bf16x8*)&sW1[((t * 3 + s) * 64 + lane) * 8], acc2[t], 0, 0, 0);
    }
    #pragma unroll
    for (int t = 0; t < 3; ++t)
      #pragma unroll
      for (int r = 0; r < 4; ++r)
        PW[OFF_H1 + (4 * g + r) * H1_STRIDE + t * 16 + c] =
            (__bf16)fmaxf(acc2[t][r] + b1_r[t], 0.f);

    // Layer 3: [16,48(->64)] @ [64,16]
    f32x4 acc3 = (f32x4){0.f, 0.f, 0.f, 0.f};
    #pragma unroll
    for (int s = 0; s < 2; ++s) {
      bf16x8 a3 = *(const bf16x8*)&PW[OFF_H1 + c * H1_STRIDE + s * 32 + g * 8];
      acc3 = __builtin_amdgcn_mfma_f32_16x16x32_bf16(a3, w2f[s], acc3, 0, 0, 0);
    }

    // Layer 4 logits + softmax over n (b3 cancels)
    float lp[4];
    #pragma unroll
    for (int r = 0; r < 4; ++r) lp[r] = fmaxf(acc3[r] + b2_r, 0.f) * w3_r;
    #pragma unroll
    for (int off = 1; off < 16; off <<= 1)
      #pragma unroll
      for (int r = 0; r < 4; ++r) lp[r] += __shfl_xor(lp[r], off);
    float mrow = fmaxf(fmaxf(lp[0], lp[1]), fmaxf(lp[2], lp[3]));
    float m = fmaxf(mrow, __shfl_xor(mrow, 16));
    m = fmaxf(m, __shfl_xor(m, 32));
    float e[4];
    #pragma unroll
    for (int r = 0; r < 4; ++r) e[r] = __expf(lp[r] - m);
    float ss = e[0] + e[1] + e[2] + e[3];
    ss += __shfl_xor(ss, 16);
    ss += __shfl_xor(ss, 32);
    const float rs = 1.f / ss;

    // Aggregate from staged LDS tile: lane handles h = {2*lane, 2*lane+1}
    #pragma unroll
    for (int n = 0; n < 16; ++n) {
      float wn = __shfl(e[n & 3], (n >> 2) << 4) * rs;
      unsigned u = *(const unsigned*)
          &PW[OFF_NE + n * 128 + (((lane >> 2) ^ n) << 3) + ((lane & 3) << 1)];
      agg0 = fmaf(wn, bf16lo(u), agg0);
      agg1 = fmaf(wn, bf16hi(u), agg1);
    }
  }

  // ---- Cross-wave reduction (4 waves per b), reuse NE region ----
  float* red = (float*)&sPW[wave][OFF_NE];
  red[2 * lane]     = agg0;
  red[2 * lane + 1] = agg1;
  __syncthreads();
  if (tid < 256) {
    int bs = tid >> 7, h = tid & 127;
    float s = 0.f;
    #pragma unroll
    for (int w = 0; w < 4; ++w) s += ((float*)&sPW[bs * 4 + w][OFF_NE])[h];
    aggmean[(size_t)(blockIdx.x * 2 + bs) * H + h] = s * (1.0f / L);
  }
}

// Kernel B: fused head. pooled = aggmean @ Wmh + bmh (mean/matmul commuted),
// comb = [user_emb, pooled], hidden = relu(comb @ Wfc1 + bfc1),
// out = sigmoid(hidden @ Wout + bout).
__global__ __launch_bounds__(128) void head_kernel(
    const int*   __restrict__ user_ids,
    const float* __restrict__ user_table,
    const float* __restrict__ aggmean,
    const float* __restrict__ Wmh,  const float* __restrict__ bmh,
    const float* __restrict__ Wfc1, const float* __restrict__ bfc1,
    const float* __restrict__ Wout, const float* __restrict__ bout,
    float* __restrict__ out)
{
  __shared__ float sComb[2 * H];
  __shared__ float sAgg[H];
  __shared__ float sRed[2];
  const int t = threadIdx.x, b = blockIdx.x;

  int uid = user_ids[b];
  sComb[t] = user_table[(size_t)uid * H + t];
  sAgg[t]  = aggmean[b * H + t];
  __syncthreads();

  float p = bmh[t];
  #pragma unroll 4
  for (int k = 0; k < H; ++k) p = fmaf(sAgg[k], Wmh[k * H + t], p);
  sComb[H + t] = p;
  __syncthreads();

  float hd = bfc1[t];
  #pragma unroll 4
  for (int k = 0; k < 2 * H; ++k) hd = fmaf(sComb[k], Wfc1[k * H + t], hd);
  hd = fmaxf(hd, 0.f);

  float v = hd * Wout[t];
  #pragma unroll
  for (int off = 32; off > 0; off >>= 1) v += __shfl_down(v, off);
  if ((t & 63) == 0) sRed[t >> 6] = v;
  __syncthreads();
  if (t == 0) {
    float s = sRed[0] + sRed[1] + bout[0];
    out[b] = 1.f / (1.f + __expf(-s));
  }
}

extern "C" void kernel_launch(void* const* d_in, const int* in_sizes, int n_in,
                              void* d_out, int out_size, void* d_ws, size_t ws_size,
                              hipStream_t stream) {
  const int*   user_ids     = (const int*)  d_in[0];
  // d_in[1] = item_ids — unused (item_emb computed but unused in reference)
  const int*   history      = (const int*)  d_in[2];
  const float* neighbor_emb = (const float*)d_in[3];
  const float* user_table   = (const float*)d_in[4];
  const float* item_table   = (const float*)d_in[5];
  const float* Wa   = (const float*)d_in[6];
  const float* ba   = (const float*)d_in[7];
  const float* W1   = (const float*)d_in[8];
  const float* b1   = (const float*)d_in[9];
  const float* W2   = (const float*)d_in[10];
  const float* b2   = (const float*)d_in[11];
  const float* W3   = (const float*)d_in[12];
  // d_in[13] = b3 — constant shift over the softmax axis, cancels exactly
  const float* Wmh  = (const float*)d_in[14];
  const float* bmh  = (const float*)d_in[15];
  const float* Wfc1 = (const float*)d_in[16];
  const float* bfc1 = (const float*)d_in[17];
  const float* Wout = (const float*)d_in[18];
  const float* bout = (const float*)d_in[19];

  float* aggmean = (float*)d_ws;     // [B][H] = 256 KB
  float* out     = (float*)d_out;    // [B]

  hipLaunchKernelGGL(attn_agg_kernel, dim3(B / 2), dim3(512), 0, stream,
                     history, neighbor_emb, item_table,
                     Wa, ba, W1, b1, W2, b2, W3, aggmean);
  hipLaunchKernelGGL(head_kernel, dim3(B), dim3(128), 0, stream,
                     user_ids, user_table, aggmean,
                     Wmh, bmh, Wfc1, bfc1, Wout, bout, out);
}